// Round 5
// baseline (250.575 us; speedup 1.0000x reference)
//
#include <hip/hip_runtime.h>
#include <math.h>

constexpr int B = 16, F = 64, E = 16, H = 64, W = 64;
constexpr int XP = 66;          // padded x dim (1 zero col each side)
constexpr int CP = 72;          // LDS c-dim pad (2-way bank aliasing only)
constexpr int YSTRIDE = XP * F; // 4224 elems per (b,y) row in transposed bufs

typedef __bf16 bf16x8 __attribute__((ext_vector_type(8)));
typedef __bf16 bf16x4 __attribute__((ext_vector_type(4)));
typedef float f32x16 __attribute__((ext_vector_type(16)));
typedef float f32x4 __attribute__((ext_vector_type(4)));

// Monotone grid barrier: each launch's 512 blocks hit each barrier exactly once,
// so the counter advances by an aligned 512-window per barrier. Target derived
// from atomicAdd's return => no reset needed, graph-replay safe, no static state
// beyond the monotone counter (zero-init at module load).
__device__ unsigned long long g_bar = 0;

__device__ __forceinline__ void grid_barrier() {
    __syncthreads();   // drains this wave's vmem (compiler emits vmcnt(0) before s_barrier)
    if (threadIdx.x == 0) {
        __threadfence();                       // device-scope release (cross-XCD L2 wb)
        unsigned long long ret =
            __hip_atomic_fetch_add(&g_bar, 1ull, __ATOMIC_ACQ_REL, __HIP_MEMORY_SCOPE_AGENT);
        unsigned long long target = (ret & ~511ull) + 512ull;
        while (__hip_atomic_load(&g_bar, __ATOMIC_ACQUIRE, __HIP_MEMORY_SCOPE_AGENT) < target)
            __builtin_amdgcn_s_sleep(2);
        __threadfence();                       // device-scope acquire (L2 inv)
    }
    __syncthreads();
}

// ---------------------------------------------------------------------------
// One persistent kernel, 512 blocks (>=2/CU guaranteed: LDS 38.9KB, VGPR<=256):
//  P0: transpose state->xTs bf16 + repack weights + zero out   | barrier
//  P1: conv1 (MFMA 32x32x16) xTs->xT1                          | barrier
//  P2: conv2 (MFMA 16x16x32) -> attn (global + LDS), then
//      sproj (MFMA from xTs) + relu-reduce, atomicAdd -> out
// ---------------------------------------------------------------------------
__global__ __launch_bounds__(256, 2) void fused_all(
    const float* __restrict__ state, const float* __restrict__ pre_w,
    const float* __restrict__ pre_b, const float* __restrict__ attn_w,
    const float* __restrict__ attn_b, const float* __restrict__ c3_w,
    const float* __restrict__ c3_b,
    __bf16* __restrict__ xTs, __bf16* __restrict__ xT1,
    __bf16* __restrict__ wA1, __bf16* __restrict__ wA2,
    __bf16* __restrict__ wT3b,
    float* __restrict__ out, float* __restrict__ attn_out)
{
    __shared__ __align__(16) char smem[38912];
    const int blk = blockIdx.x;
    const int tid = threadIdx.x;
    const int b = blk >> 5, yp = blk & 31;     // 32 row-pair slots per batch
    const int wave = tid >> 6, lane = tid & 63;

    // ---------------- P0: transpose + repack + zero out ----------------
    {
        float (*ts)[64][68] = (float(*)[64][68])smem;   // [2][64][68] fp32
        {
            int c = tid >> 2, x0 = (tid & 3) * 16;
            #pragma unroll
            for (int rr = 0; rr < 2; ++rr) {
                const float* src = state + ((size_t)(b * F + c) * H + (yp * 2 + rr)) * W + x0;
                #pragma unroll
                for (int q = 0; q < 4; ++q)
                    *(float4*)&ts[rr][c][x0 + 4 * q] = *(const float4*)(src + 4 * q);
            }
        }
        __syncthreads();
        #pragma unroll
        for (int rr = 0; rr < 2; ++rr) {
            __bf16* dst = xTs + (size_t)(b * H + yp * 2 + rr) * YSTRIDE;
            #pragma unroll
            for (int i = 0; i < 2; ++i) {
                int t = tid + i * 256;
                int x = t >> 3, cg = t & 7;
                bf16x8 v;
                #pragma unroll
                for (int j = 0; j < 8; ++j) v[j] = (__bf16)ts[rr][cg * 8 + j][x];
                *(bf16x8*)(dst + (x + 1) * F + cg * 8) = v;
            }
            if (tid < 16) {
                int bd = tid >> 3, cg = tid & 7;
                bf16x8 z = {};
                *(bf16x8*)(dst + (bd ? 65 : 0) * F + cg * 8) = z;
            }
        }
        if (blk < 144) {
            int idx = blk * 256 + tid;
            if (idx < 64 * 576) {
                int o = idx / 576, rem = idx - o * 576, t = rem >> 6, c = rem & 63;
                wA1[idx] = (__bf16)pre_w[(o * 64 + c) * 9 + t];
            }
            if (idx < 16 * 576) {
                int e = idx / 576, rem = idx - e * 576, t = rem >> 6, c = rem & 63;
                wA2[idx] = (__bf16)attn_w[(e * 64 + c) * 9 + t];
            }
            if (idx < 64 * 64) wT3b[idx] = (__bf16)c3_w[idx];  // already [o][f]
        } else if (blk < 160) {
            int idx = (blk - 144) * 256 + tid;   // 16 blocks x 1024 floats
            float4 z = {0.f, 0.f, 0.f, 0.f};
            *(float4*)(out + idx * 4) = z;
        }
    }
    grid_barrier();

    // ---------------- P1: conv1 (identical math to prior conv1_mfma) --------
    {
        __bf16* sx = (__bf16*)smem;
        const int y0 = yp * 2;
        for (int t = tid; t < 4 * XP * 8; t += 256) {
            int r = t / (XP * 8), rem = t - r * (XP * 8);
            int x = rem >> 3, cg = rem & 7;
            int yy = y0 - 1 + r;
            bf16x8 v = {};
            if (yy >= 0 && yy < H)
                v = *(const bf16x8*)(xTs + (size_t)(b * H + yy) * YSTRIDE + x * F + cg * 8);
            *(bf16x8*)(sx + (r * XP + x) * CP + cg * 8) = v;
        }
        __syncthreads();

        const int mt = wave & 1, np = wave >> 1;
        const int n = lane & 31, kh = lane >> 5;
        f32x16 acc0 = {}, acc1 = {};
        const __bf16* aBase = wA1 + (mt * 32 + n) * 576 + kh * 8;
        #pragma unroll
        for (int dy = 0; dy < 3; ++dy)
            #pragma unroll
            for (int dx = 0; dx < 3; ++dx) {
                const int t9 = dy * 3 + dx;
                const __bf16* bBase = sx + ((np + dy) * XP + (n + dx)) * CP + kh * 8;
                #pragma unroll
                for (int cq = 0; cq < 4; ++cq) {
                    bf16x8 a  = *(const bf16x8*)(aBase + t9 * 64 + cq * 16);
                    bf16x8 b0 = *(const bf16x8*)(bBase + cq * 16);
                    bf16x8 b1 = *(const bf16x8*)(bBase + 32 * CP + cq * 16);
                    acc0 = __builtin_amdgcn_mfma_f32_32x32x16_bf16(a, b0, acc0, 0, 0, 0);
                    acc1 = __builtin_amdgcn_mfma_f32_32x32x16_bf16(a, b1, acc1, 0, 0, 0);
                }
            }
        __bf16* obase = xT1 + (size_t)(b * H + y0 + np) * YSTRIDE;
        #pragma unroll
        for (int g = 0; g < 4; ++g) {
            int o0 = mt * 32 + kh * 4 + g * 8;
            f32x4 b4 = *(const f32x4*)(pre_b + o0);
            bf16x4 v0, v1;
            #pragma unroll
            for (int r = 0; r < 4; ++r) {
                v0[r] = (__bf16)fmaxf(acc0[g * 4 + r] + b4[r], 0.f);
                v1[r] = (__bf16)fmaxf(acc1[g * 4 + r] + b4[r], 0.f);
            }
            *(bf16x4*)(obase + (n + 1) * F + o0) = v0;
            *(bf16x4*)(obase + (n + 33) * F + o0) = v1;
        }
        if (tid < 32) {
            int r2 = tid >> 4, bd = (tid >> 3) & 1, cg = tid & 7;
            bf16x8 z = {};
            *(bf16x8*)(xT1 + (size_t)(b * H + y0 + r2) * YSTRIDE + (bd ? 65 : 0) * F + cg * 8) = z;
        }
    }
    grid_barrier();

    // ---------------- P2: conv2 + sproj + reduce (row-local fusion) ---------
    {
        __bf16* sx = (__bf16*)smem;
        float (*s_attn)[64][16] = (float(*)[64][16])smem;        // [2][64][16]
        float (*s_sp)[68] = (float(*)[68])(smem + 8192);         // [64][68]
        const int y0 = yp * 2;

        for (int t = tid; t < 4 * XP * 8; t += 256) {
            int r = t / (XP * 8), rem = t - r * (XP * 8);
            int x = rem >> 3, cg = rem & 7;
            int yy = y0 - 1 + r;
            bf16x8 v = {};
            if (yy >= 0 && yy < H)
                v = *(const bf16x8*)(xT1 + (size_t)(b * H + yy) * YSTRIDE + x * F + cg * 8);
            *(bf16x8*)(sx + (r * XP + x) * CP + cg * 8) = v;
        }
        __syncthreads();

        // conv2: wave = (row rw, x-half nt2); M=16(E) x N=32 via 2 n-tiles
        const int rw = wave >> 1, nt2 = wave & 1;
        const int n16 = lane & 15, quad = lane >> 4;
        f32x4 acc2[2] = {};
        {
            const __bf16* aB = wA2 + n16 * 576 + quad * 8;
            #pragma unroll
            for (int dy = 0; dy < 3; ++dy)
                #pragma unroll
                for (int dx = 0; dx < 3; ++dx) {
                    const int t9 = dy * 3 + dx;
                    #pragma unroll
                    for (int cq = 0; cq < 2; ++cq) {
                        bf16x8 a = *(const bf16x8*)(aB + t9 * 64 + cq * 32);
                        #pragma unroll
                        for (int i = 0; i < 2; ++i) {
                            const __bf16* bp = sx +
                                ((rw + dy) * XP + (nt2 * 32 + i * 16 + n16 + dx)) * CP
                                + quad * 8 + cq * 32;
                            acc2[i] = __builtin_amdgcn_mfma_f32_16x16x32_bf16(
                                a, *(const bf16x8*)bp, acc2[i], 0, 0, 0);
                        }
                    }
                }
        }
        __syncthreads();   // all waves done reading sx; s_attn overlays it

        #pragma unroll
        for (int i = 0; i < 2; ++i) {
            int x = nt2 * 32 + i * 16 + n16;
            #pragma unroll
            for (int r = 0; r < 4; ++r) {
                int e = quad * 4 + r;
                float val = acc2[i][r] + attn_b[e];
                float sg = 1.f / (1.f + __expf(-val));
                attn_out[((size_t)(b * E + e) * H + (y0 + rw)) * W + x] = sg;
                s_attn[rw][x][e] = sg;
            }
        }
        __syncthreads();

        const int combo = tid & 63;
        const int eg = combo >> 4, og = combo & 15, psub = tid >> 6;
        f32x4 cb4 = ((const f32x4*)c3_b)[og];
        float vsum[4] = {0.f, 0.f, 0.f, 0.f};

        for (int rr = 0; rr < 2; ++rr) {
            {   // sproj via MFMA from xTs row y0+rr
                const int mt = wave & 1, nt = wave >> 1;
                const int n = lane & 31, kh = lane >> 5;
                const __bf16* bBase = xTs + (size_t)(b * H + y0 + rr) * YSTRIDE
                                      + (nt * 32 + n + 1) * F + kh * 8;
                const __bf16* aBase = wT3b + (mt * 32 + n) * 64 + kh * 8;
                f32x16 acc = {};
                #pragma unroll
                for (int cq = 0; cq < 4; ++cq) {
                    bf16x8 a  = *(const bf16x8*)(aBase + cq * 16);
                    bf16x8 bb = *(const bf16x8*)(bBase + cq * 16);
                    acc = __builtin_amdgcn_mfma_f32_32x32x16_bf16(a, bb, acc, 0, 0, 0);
                }
                #pragma unroll
                for (int g = 0; g < 4; ++g)
                    #pragma unroll
                    for (int r = 0; r < 4; ++r)
                        s_sp[nt * 32 + n][mt * 32 + kh * 4 + g * 8 + r] = acc[g * 4 + r];
            }
            __syncthreads();

            float accl[4][4] = {};
            #pragma unroll 2
            for (int pp = 0; pp < 16; ++pp) {
                int p = psub * 16 + pp;
                f32x4 a4 = *(const f32x4*)&s_attn[rr][p][eg * 4];
                f32x4 s4 = *(const f32x4*)&s_sp[p][og * 4];
                #pragma unroll
                for (int i = 0; i < 4; ++i)
                    #pragma unroll
                    for (int j = 0; j < 4; ++j)
                        accl[i][j] += fmaxf(fmaf(a4[i], s4[j], cb4[j]), 0.f);
            }
            __syncthreads();
            float* s_part = &s_sp[0][0];           // 4096 floats, overlays s_sp
            #pragma unroll
            for (int i = 0; i < 4; ++i)
                #pragma unroll
                for (int j = 0; j < 4; ++j)
                    s_part[(psub * 64 + combo) * 16 + i * 4 + j] = accl[i][j];
            __syncthreads();
            {
                int cmb = tid >> 2, ii = tid & 3;
                #pragma unroll
                for (int j = 0; j < 4; ++j) {
                    float v = 0.f;
                    #pragma unroll
                    for (int ps = 0; ps < 4; ++ps)
                        v += s_part[(ps * 64 + cmb) * 16 + ii * 4 + j];
                    vsum[j] += v;
                }
            }
            __syncthreads();   // s_part reads done before next rr overwrites s_sp
        }
        {
            int cmb = tid >> 2, ii = tid & 3;
            int e = (cmb >> 4) * 4 + ii;
            #pragma unroll
            for (int j = 0; j < 4; ++j) {
                int o = (cmb & 15) * 4 + j;
                float add = vsum[j] * (1.f / 4356.f);
                if (yp == 0) add += 260.f * fmaxf(c3_b[o], 0.f) * (1.f / 4356.f);
                atomicAdd(&out[(b * E + e) * F + o], add);
            }
        }
    }
}

// ---------------------------------------------------------------------------
extern "C" void kernel_launch(void* const* d_in, const int* in_sizes, int n_in,
                              void* d_out, int out_size, void* d_ws, size_t ws_size,
                              hipStream_t stream) {
    (void)in_sizes; (void)n_in; (void)out_size; (void)ws_size;
    const float* state  = (const float*)d_in[0];
    const float* pre_w  = (const float*)d_in[1];
    const float* pre_b  = (const float*)d_in[2];
    const float* attn_w = (const float*)d_in[3];
    const float* attn_b = (const float*)d_in[4];
    const float* c3_w   = (const float*)d_in[5];
    const float* c3_b   = (const float*)d_in[6];

    float* out      = (float*)d_out;
    float* attn_out = out + B * E * F;

    char* ws = (char*)d_ws;
    constexpr size_t XT_BYTES = (size_t)B * H * YSTRIDE * 2;   // 8,650,752
    __bf16* xTs  = (__bf16*)ws;
    __bf16* xT1  = (__bf16*)(ws + XT_BYTES);
    __bf16* wA1  = (__bf16*)(ws + 2 * XT_BYTES);
    __bf16* wA2  = (__bf16*)(ws + 2 * XT_BYTES + 73728);
    __bf16* wT3b = (__bf16*)(ws + 2 * XT_BYTES + 73728 + 18432);

    fused_all<<<512, 256, 0, stream>>>(state, pre_w, pre_b, attn_w, attn_b,
                                       c3_w, c3_b, xTs, xT1, wA1, wA2, wT3b,
                                       out, attn_out);
}

// Round 6
// 116.415 us; speedup vs baseline: 2.1524x; 2.1524x over previous
//
#include <hip/hip_runtime.h>
#include <math.h>

constexpr int B = 16, F = 64, E = 16, H = 64, W = 64;
constexpr int XP = 66;          // padded x dim (1 zero col each side)
constexpr int CP = 72;          // LDS c-dim pad (2-way bank aliasing only)
constexpr int YSTRIDE = XP * F; // 4224 elems per (b,y) row in transposed bufs

typedef __bf16 bf16x8 __attribute__((ext_vector_type(8)));
typedef __bf16 bf16x4 __attribute__((ext_vector_type(4)));
typedef float f32x16 __attribute__((ext_vector_type(16)));
typedef float f32x4 __attribute__((ext_vector_type(4)));

// ---------------------------------------------------------------------------
// prep: blk<1024: transpose state -> xTs[b][y][x+1][c] bf16 (borders zeroed)
//       blk<1168: repack weights (wA1[o][t*64+c], wA2[e][t*64+c], wT3b=bf16(c3_w))
//       else    : zero d_out[0..16383] (the (B,E,F) accumulator region)
// ---------------------------------------------------------------------------
__global__ __launch_bounds__(256) void prep_kernel(
    const float* __restrict__ state, const float* __restrict__ pre_w,
    const float* __restrict__ attn_w, const float* __restrict__ c3_w,
    __bf16* __restrict__ xTs, __bf16* __restrict__ wA1,
    __bf16* __restrict__ wA2, __bf16* __restrict__ wT3b,
    float* __restrict__ out0)
{
    __shared__ float s_t[64][68];
    const int blk = blockIdx.x;
    const int tid = threadIdx.x;

    if (blk < 1024) {
        const int b = blk >> 6, y = blk & 63;
        {
            int c = tid >> 2, x0 = (tid & 3) * 16;
            const float* src = state + ((size_t)(b * F + c) * H + y) * W + x0;
            #pragma unroll
            for (int q = 0; q < 4; ++q)
                *(float4*)&s_t[c][x0 + 4 * q] = *(const float4*)(src + 4 * q);
        }
        __syncthreads();
        __bf16* dst = xTs + (size_t)(b * H + y) * YSTRIDE;
        #pragma unroll
        for (int i = 0; i < 2; ++i) {
            int t = tid + i * 256;
            int x = t >> 3, cg = t & 7;
            bf16x8 v;
            #pragma unroll
            for (int j = 0; j < 8; ++j) v[j] = (__bf16)s_t[cg * 8 + j][x];
            *(bf16x8*)(dst + (x + 1) * F + cg * 8) = v;
        }
        if (tid < 16) {
            int bd = tid >> 3, cg = tid & 7;
            bf16x8 z = {};
            *(bf16x8*)(dst + (bd ? 65 : 0) * F + cg * 8) = z;
        }
    } else if (blk < 1168) {
        int idx = (blk - 1024) * 256 + tid;
        if (idx < 64 * 576) {
            int o = idx / 576, rem = idx - o * 576, t = rem >> 6, c = rem & 63;
            wA1[idx] = (__bf16)pre_w[(o * 64 + c) * 9 + t];
        }
        if (idx < 16 * 576) {
            int e = idx / 576, rem = idx - e * 576, t = rem >> 6, c = rem & 63;
            wA2[idx] = (__bf16)attn_w[(e * 64 + c) * 9 + t];
        }
        if (idx < 64 * 64) {
            wT3b[idx] = (__bf16)c3_w[idx];   // already [o][f] row-major
        }
    } else {
        int idx = (blk - 1168) * 256 + tid;  // 16 blocks cover 16384 floats
        float4 z = {0.f, 0.f, 0.f, 0.f};
        *(float4*)(out0 + idx * 4) = z;
    }
}

// ---------------------------------------------------------------------------
// conv1 via MFMA 32x32x16 bf16: 9 taps x 4 c-chunks of K=16, accumulated.
// block = (2 rows, all 64 out ch); wave = M32 x N64 (one row, both halves).
// out written transposed bf16 -> xT1[b][y][x+1][o], borders zeroed.
// ---------------------------------------------------------------------------
__global__ __launch_bounds__(256) void conv1_mfma(
    const __bf16* __restrict__ xTs, const __bf16* __restrict__ wA1,
    const float* __restrict__ bias, __bf16* __restrict__ xT1)
{
    __shared__ __bf16 s_x[4 * XP * CP];
    const int b = blockIdx.y, y0 = blockIdx.x * 2;
    const int tid = threadIdx.x;

    for (int t = tid; t < 4 * XP * 8; t += 256) {
        int r = t / (XP * 8);
        int rem = t - r * (XP * 8);
        int x = rem >> 3, cg = rem & 7;
        int yy = y0 - 1 + r;
        bf16x8 v = {};
        if (yy >= 0 && yy < H)
            v = *(const bf16x8*)(xTs + (size_t)(b * H + yy) * YSTRIDE + x * F + cg * 8);
        *(bf16x8*)(s_x + (r * XP + x) * CP + cg * 8) = v;
    }
    __syncthreads();

    const int wave = tid >> 6, lane = tid & 63;
    const int mt = wave & 1;      // M-tile (o 0..31 / 32..63)
    const int np = wave >> 1;     // which of the 2 rows
    const int n = lane & 31, kh = lane >> 5;
    f32x16 acc0 = {}, acc1 = {};
    const __bf16* aBase = wA1 + (mt * 32 + n) * 576 + kh * 8;

    #pragma unroll
    for (int dy = 0; dy < 3; ++dy) {
        #pragma unroll
        for (int dx = 0; dx < 3; ++dx) {
            const int t9 = dy * 3 + dx;
            const __bf16* bBase = s_x + ((np + dy) * XP + (n + dx)) * CP + kh * 8;
            #pragma unroll
            for (int cq = 0; cq < 4; ++cq) {
                bf16x8 a  = *(const bf16x8*)(aBase + t9 * 64 + cq * 16);
                bf16x8 b0 = *(const bf16x8*)(bBase + cq * 16);
                bf16x8 b1 = *(const bf16x8*)(bBase + 32 * CP + cq * 16);
                acc0 = __builtin_amdgcn_mfma_f32_32x32x16_bf16(a, b0, acc0, 0, 0, 0);
                acc1 = __builtin_amdgcn_mfma_f32_32x32x16_bf16(a, b1, acc1, 0, 0, 0);
            }
        }
    }

    // epilogue: D row = (reg&3) + 8*(reg>>2) + 4*kh (+ mt*32), col = n
    __bf16* obase = xT1 + (size_t)(b * H + y0 + np) * YSTRIDE;
    #pragma unroll
    for (int g = 0; g < 4; ++g) {
        int o0 = mt * 32 + kh * 4 + g * 8;
        f32x4 b4 = *(const f32x4*)(bias + o0);
        bf16x4 v0, v1;
        #pragma unroll
        for (int r = 0; r < 4; ++r) {
            v0[r] = (__bf16)fmaxf(acc0[g * 4 + r] + b4[r], 0.f);
            v1[r] = (__bf16)fmaxf(acc1[g * 4 + r] + b4[r], 0.f);
        }
        *(bf16x4*)(obase + (n + 1) * F + o0) = v0;
        *(bf16x4*)(obase + (n + 33) * F + o0) = v1;
    }
    if (tid < 32) {  // zero x-borders of this block's 2 rows
        int r2 = tid >> 4, bd = (tid >> 3) & 1, cg = tid & 7;
        bf16x8 z = {};
        *(bf16x8*)(xT1 + (size_t)(b * H + y0 + r2) * YSTRIDE + (bd ? 65 : 0) * F + cg * 8) = z;
    }
}

// ---------------------------------------------------------------------------
// conv2 + sproj + reduce fused (row-local; proven as R5's P2 phase).
// block = (b, row-pair yp). conv2: MFMA 16x16x32 -> sigmoid -> attn_out + LDS.
// sproj: MFMA 32x32x16 from xTs + bf16(c3_w). reduce: relu-sum -> atomicAdd.
// ---------------------------------------------------------------------------
__global__ __launch_bounds__(256) void conv2_reduce(
    const __bf16* __restrict__ xT1, const __bf16* __restrict__ xTs,
    const __bf16* __restrict__ wA2, const __bf16* __restrict__ wT3b,
    const float* __restrict__ attn_b, const float* __restrict__ c3_b,
    float* __restrict__ attn_out, float* __restrict__ out)
{
    __shared__ __align__(16) char smem[38912];
    const int b = blockIdx.y, yp = blockIdx.x;
    const int tid = threadIdx.x;
    const int wave = tid >> 6, lane = tid & 63;
    const int y0 = yp * 2;

    __bf16* sx = (__bf16*)smem;                              // [4][XP][CP] bf16
    float (*s_attn)[64][16] = (float(*)[64][16])smem;        // [2][64][16]
    float (*s_sp)[68] = (float(*)[68])(smem + 8192);         // [64][68]

    for (int t = tid; t < 4 * XP * 8; t += 256) {
        int r = t / (XP * 8), rem = t - r * (XP * 8);
        int x = rem >> 3, cg = rem & 7;
        int yy = y0 - 1 + r;
        bf16x8 v = {};
        if (yy >= 0 && yy < H)
            v = *(const bf16x8*)(xT1 + (size_t)(b * H + yy) * YSTRIDE + x * F + cg * 8);
        *(bf16x8*)(sx + (r * XP + x) * CP + cg * 8) = v;
    }
    __syncthreads();

    // conv2: wave = (row rw, x-half nt2); M=16(E) x N=32 via 2 n-tiles
    const int rw = wave >> 1, nt2 = wave & 1;
    const int n16 = lane & 15, quad = lane >> 4;
    f32x4 acc2[2] = {};
    {
        const __bf16* aB = wA2 + n16 * 576 + quad * 8;
        #pragma unroll
        for (int dy = 0; dy < 3; ++dy)
            #pragma unroll
            for (int dx = 0; dx < 3; ++dx) {
                const int t9 = dy * 3 + dx;
                #pragma unroll
                for (int cq = 0; cq < 2; ++cq) {
                    bf16x8 a = *(const bf16x8*)(aB + t9 * 64 + cq * 32);
                    #pragma unroll
                    for (int i = 0; i < 2; ++i) {
                        const __bf16* bp = sx +
                            ((rw + dy) * XP + (nt2 * 32 + i * 16 + n16 + dx)) * CP
                            + quad * 8 + cq * 32;
                        acc2[i] = __builtin_amdgcn_mfma_f32_16x16x32_bf16(
                            a, *(const bf16x8*)bp, acc2[i], 0, 0, 0);
                    }
                }
            }
    }
    __syncthreads();   // all waves done reading sx; s_attn overlays it

    #pragma unroll
    for (int i = 0; i < 2; ++i) {
        int x = nt2 * 32 + i * 16 + n16;
        #pragma unroll
        for (int r = 0; r < 4; ++r) {
            int e = quad * 4 + r;
            float val = acc2[i][r] + attn_b[e];
            float sg = 1.f / (1.f + __expf(-val));
            attn_out[((size_t)(b * E + e) * H + (y0 + rw)) * W + x] = sg;
            s_attn[rw][x][e] = sg;
        }
    }
    __syncthreads();

    const int combo = tid & 63;
    const int eg = combo >> 4, og = combo & 15, psub = tid >> 6;
    f32x4 cb4 = ((const f32x4*)c3_b)[og];
    float vsum[4] = {0.f, 0.f, 0.f, 0.f};

    for (int rr = 0; rr < 2; ++rr) {
        {   // sproj via MFMA from xTs row y0+rr
            const int mt = wave & 1, nt = wave >> 1;
            const int n = lane & 31, kh = lane >> 5;
            const __bf16* bBase = xTs + (size_t)(b * H + y0 + rr) * YSTRIDE
                                  + (nt * 32 + n + 1) * F + kh * 8;
            const __bf16* aBase = wT3b + (mt * 32 + n) * 64 + kh * 8;
            f32x16 acc = {};
            #pragma unroll
            for (int cq = 0; cq < 4; ++cq) {
                bf16x8 a  = *(const bf16x8*)(aBase + cq * 16);
                bf16x8 bb = *(const bf16x8*)(bBase + cq * 16);
                acc = __builtin_amdgcn_mfma_f32_32x32x16_bf16(a, bb, acc, 0, 0, 0);
            }
            #pragma unroll
            for (int g = 0; g < 4; ++g)
                #pragma unroll
                for (int r = 0; r < 4; ++r)
                    s_sp[nt * 32 + n][mt * 32 + kh * 4 + g * 8 + r] = acc[g * 4 + r];
        }
        __syncthreads();

        float accl[4][4] = {};
        #pragma unroll 2
        for (int pp = 0; pp < 16; ++pp) {
            int p = psub * 16 + pp;
            f32x4 a4 = *(const f32x4*)&s_attn[rr][p][eg * 4];
            f32x4 s4 = *(const f32x4*)&s_sp[p][og * 4];
            #pragma unroll
            for (int i = 0; i < 4; ++i)
                #pragma unroll
                for (int j = 0; j < 4; ++j)
                    accl[i][j] += fmaxf(fmaf(a4[i], s4[j], cb4[j]), 0.f);
        }
        __syncthreads();
        float* s_part = &s_sp[0][0];           // 4096 floats, overlays s_sp
        #pragma unroll
        for (int i = 0; i < 4; ++i)
            #pragma unroll
            for (int j = 0; j < 4; ++j)
                s_part[(psub * 64 + combo) * 16 + i * 4 + j] = accl[i][j];
        __syncthreads();
        {
            int cmb = tid >> 2, ii = tid & 3;
            #pragma unroll
            for (int j = 0; j < 4; ++j) {
                float v = 0.f;
                #pragma unroll
                for (int ps = 0; ps < 4; ++ps)
                    v += s_part[(ps * 64 + cmb) * 16 + ii * 4 + j];
                vsum[j] += v;
            }
        }
        __syncthreads();   // s_part reads done before next rr overwrites s_sp
    }
    {
        int cmb = tid >> 2, ii = tid & 3;
        int e = (cmb >> 4) * 4 + ii;
        #pragma unroll
        for (int j = 0; j < 4; ++j) {
            int o = (cmb & 15) * 4 + j;
            float add = vsum[j] * (1.f / 4356.f);
            if (yp == 0) add += 260.f * fmaxf(c3_b[o], 0.f) * (1.f / 4356.f);
            atomicAdd(&out[(b * E + e) * F + o], add);
        }
    }
}

// ---------------------------------------------------------------------------
extern "C" void kernel_launch(void* const* d_in, const int* in_sizes, int n_in,
                              void* d_out, int out_size, void* d_ws, size_t ws_size,
                              hipStream_t stream) {
    (void)in_sizes; (void)n_in; (void)out_size; (void)ws_size;
    const float* state  = (const float*)d_in[0];
    const float* pre_w  = (const float*)d_in[1];
    const float* pre_b  = (const float*)d_in[2];
    const float* attn_w = (const float*)d_in[3];
    const float* attn_b = (const float*)d_in[4];
    const float* c3_w   = (const float*)d_in[5];
    const float* c3_b   = (const float*)d_in[6];

    float* out      = (float*)d_out;
    float* attn_out = out + B * E * F;

    char* ws = (char*)d_ws;
    constexpr size_t XT_BYTES = (size_t)B * H * YSTRIDE * 2;   // 8,650,752
    __bf16* xTs  = (__bf16*)ws;
    __bf16* xT1  = (__bf16*)(ws + XT_BYTES);
    __bf16* wA1  = (__bf16*)(ws + 2 * XT_BYTES);
    __bf16* wA2  = (__bf16*)(ws + 2 * XT_BYTES + 73728);
    __bf16* wT3b = (__bf16*)(ws + 2 * XT_BYTES + 73728 + 18432);

    prep_kernel<<<1184, 256, 0, stream>>>(state, pre_w, attn_w, c3_w,
                                          xTs, wA1, wA2, wT3b, out);
    conv1_mfma<<<dim3(H / 2, B), 256, 0, stream>>>(xTs, wA1, pre_b, xT1);
    conv2_reduce<<<dim3(H / 2, B), 256, 0, stream>>>(xT1, xTs, wA2, wT3b,
                                                     attn_b, c3_b, attn_out, out);
}